// Round 1
// baseline (1074.769 us; speedup 1.0000x reference)
//
#include <hip/hip_runtime.h>

// QuantizedLinear: y[b,s,o] = sum_i x[b,s,i] * (q[o*K+i]/7 * absmax[(o*K+i)/64]) + bias[o]
// M=8192, K=4096, N=11008. Strategy: dequant W -> fp16 [N][K] in ws, cvt x -> fp16 [M][K] in ws,
// then m97-structure fp16 MFMA GEMM (128x128 tile, BK=32, 4 waves, global_load_lds w=16).

#define K_DIM 4096
#define N_DIM 11008
#define M_DIM 8192

typedef _Float16 f16;
typedef _Float16 f16x8 __attribute__((ext_vector_type(8)));
typedef float f32x4 __attribute__((ext_vector_type(4)));

__device__ __forceinline__ void gload16(const void* g, void* lds) {
  __builtin_amdgcn_global_load_lds(
      (__attribute__((address_space(1))) void*)g,
      (__attribute__((address_space(3))) void*)lds,
      16, 0, 0);
}

// x f32 -> f16, 8 elems/thread
__global__ __launch_bounds__(256) void cvt_x_kernel(const float* __restrict__ x,
                                                    f16* __restrict__ xo, int n8) {
  int i = blockIdx.x * blockDim.x + threadIdx.x;
  if (i >= n8) return;
  const float4* xv = (const float4*)x;
  float4 a = xv[2 * i];
  float4 b = xv[2 * i + 1];
  f16x8 o;
  o[0] = (f16)a.x; o[1] = (f16)a.y; o[2] = (f16)a.z; o[3] = (f16)a.w;
  o[4] = (f16)b.x; o[5] = (f16)b.y; o[6] = (f16)b.z; o[7] = (f16)b.w;
  *(f16x8*)(xo + (size_t)i * 8) = o;
}

// int32 codes + per-64-block absmax -> f16 weights, 8 elems/thread (all 8 in same block)
__global__ __launch_bounds__(256) void dequant_kernel(const int* __restrict__ q,
                                                      const float* __restrict__ amax,
                                                      f16* __restrict__ wo, int n8) {
  int i = blockIdx.x * blockDim.x + threadIdx.x;
  if (i >= n8) return;
  const int4* qv = (const int4*)q;
  int4 a = qv[2 * i];
  int4 b = qv[2 * i + 1];
  float s = amax[i >> 3] * (1.0f / 7.0f);
  f16x8 o;
  o[0] = (f16)((float)a.x * s); o[1] = (f16)((float)a.y * s);
  o[2] = (f16)((float)a.z * s); o[3] = (f16)((float)a.w * s);
  o[4] = (f16)((float)b.x * s); o[5] = (f16)((float)b.y * s);
  o[6] = (f16)((float)b.z * s); o[7] = (f16)((float)b.w * s);
  *(f16x8*)(wo + (size_t)i * 8) = o;
}

// C[M][N] = A[M][K] * B[N][K]^T + bias ; 128x128 tile, BK=32, 256 threads (4 waves 2x2)
__global__ __launch_bounds__(256) void gemm_f16_bt(const f16* __restrict__ A,
                                                   const f16* __restrict__ B,
                                                   const float* __restrict__ bias,
                                                   float* __restrict__ C) {
  __shared__ __align__(16) f16 As[128 * 32];
  __shared__ __align__(16) f16 Bs[128 * 32];
  const int t = threadIdx.x;
  const int w = t >> 6;
  const int l = t & 63;
  const int m0 = blockIdx.y * 128;
  const int n0 = blockIdx.x * 128;
  const int wr = w >> 1, wc = w & 1;  // 2x2 wave grid, each wave does 64x64

  f32x4 acc[4][4];
#pragma unroll
  for (int m = 0; m < 4; ++m)
#pragma unroll
    for (int n = 0; n < 4; ++n) acc[m][n] = (f32x4){0.f, 0.f, 0.f, 0.f};

  // staging: 8KB tile = 8 chunks of 1024B; wave w stages chunks w and w+4.
  // lane l's bytes: chunk*1024 + l*16 -> row = bo/64 (64B per 32-f16 row), col = (bo%64)/2
  const int c0 = w, c1 = w + 4;
  const int bo0 = c0 * 1024 + l * 16;
  const int bo1 = c1 * 1024 + l * 16;
  const int row0 = bo0 >> 6, col0 = (bo0 & 63) >> 1;
  const int row1 = bo1 >> 6, col1 = (bo1 & 63) >> 1;

  const f16* Ab0 = A + (size_t)(m0 + row0) * K_DIM + col0;
  const f16* Ab1 = A + (size_t)(m0 + row1) * K_DIM + col1;
  const f16* Bb0 = B + (size_t)(n0 + row0) * K_DIM + col0;
  const f16* Bb1 = B + (size_t)(n0 + row1) * K_DIM + col1;
  char* AsB = (char*)As;
  char* BsB = (char*)Bs;

  const int lr = l & 15;        // fragment row (A) / col (B)
  const int lk = (l >> 4) * 8;  // fragment k-offset (elements)

  for (int k0 = 0; k0 < K_DIM; k0 += 32) {
    gload16(Ab0 + k0, AsB + c0 * 1024);
    gload16(Ab1 + k0, AsB + c1 * 1024);
    gload16(Bb0 + k0, BsB + c0 * 1024);
    gload16(Bb1 + k0, BsB + c1 * 1024);
    __syncthreads();  // emits vmcnt(0) drain — known m97 structural stall

    f16x8 af[4], bf[4];
#pragma unroll
    for (int m = 0; m < 4; ++m)
      af[m] = *(const f16x8*)(As + (wr * 64 + m * 16 + lr) * 32 + lk);
#pragma unroll
    for (int n = 0; n < 4; ++n)
      bf[n] = *(const f16x8*)(Bs + (wc * 64 + n * 16 + lr) * 32 + lk);
#pragma unroll
    for (int m = 0; m < 4; ++m)
#pragma unroll
      for (int n = 0; n < 4; ++n)
        acc[m][n] = __builtin_amdgcn_mfma_f32_16x16x32_f16(af[m], bf[n], acc[m][n], 0, 0, 0);
    __syncthreads();
  }

  // epilogue: C/D layout col = lane&15, row = (lane>>4)*4 + j  [measured m89/m91]
  const int orow = (l >> 4) * 4;
  float bv[4];
#pragma unroll
  for (int n = 0; n < 4; ++n) bv[n] = bias[n0 + wc * 64 + n * 16 + lr];
#pragma unroll
  for (int m = 0; m < 4; ++m) {
#pragma unroll
    for (int n = 0; n < 4; ++n) {
      const size_t cb = (size_t)(m0 + wr * 64 + m * 16 + orow) * N_DIM + (n0 + wc * 64 + n * 16 + lr);
#pragma unroll
      for (int j = 0; j < 4; ++j) C[cb + (size_t)j * N_DIM] = acc[m][n][j] + bv[n];
    }
  }
}

extern "C" void kernel_launch(void* const* d_in, const int* in_sizes, int n_in,
                              void* d_out, int out_size, void* d_ws, size_t ws_size,
                              hipStream_t stream) {
  const float* x = (const float*)d_in[0];
  const int* wq = (const int*)d_in[1];
  const float* amax = (const float*)d_in[2];
  const float* bias = (const float*)d_in[3];
  float* out = (float*)d_out;

  f16* Xh = (f16*)d_ws;                                        // 8192*4096*2 = 64 MB
  f16* Wh = (f16*)((char*)d_ws + (size_t)M_DIM * K_DIM * 2);   // 11008*4096*2 = 90 MB

  {
    int n8 = M_DIM * K_DIM / 8;  // 4194304
    cvt_x_kernel<<<n8 / 256, 256, 0, stream>>>(x, Xh, n8);
  }
  {
    int n8 = N_DIM * K_DIM / 8;  // 5636096
    dequant_kernel<<<n8 / 256, 256, 0, stream>>>(wq, amax, Wh, n8);
  }
  {
    dim3 grid(N_DIM / 128, M_DIM / 128);  // 86 x 64
    gemm_f16_bt<<<grid, 256, 0, stream>>>(Xh, Wh, bias, out);
  }
}

// Round 2
// 815.996 us; speedup vs baseline: 1.3171x; 1.3171x over previous
//
#include <hip/hip_runtime.h>

// QuantizedLinear M=8192 K=4096 N=11008.
// Prepass: dequant int4-blockwise W -> f16 [N][K]; cvt x -> f16 [M][K].
// GEMM: 256x256 tile, BK=64, 512 thr (8 waves 2Mx4N), deep-pipelined 4-phase/K-tile,
// counted vmcnt(4), XOR-swizzled LDS (linear gload_lds dest + pre-swizzled global src),
// setprio around MFMA, bijective XCD blockIdx swizzle.

#define K_DIM 4096
#define N_DIM 11008
#define M_DIM 8192
#define NT_K 64  // K_DIM / 64

typedef _Float16 f16;
typedef _Float16 f16x8 __attribute__((ext_vector_type(8)));
typedef float f32x4 __attribute__((ext_vector_type(4)));

__device__ __forceinline__ void gload16(const void* g, void* lds) {
  __builtin_amdgcn_global_load_lds(
      (__attribute__((address_space(1))) void*)g,
      (__attribute__((address_space(3))) void*)lds,
      16, 0, 0);
}

__global__ __launch_bounds__(256) void cvt_x_kernel(const float* __restrict__ x,
                                                    f16* __restrict__ xo, int n8) {
  int i = blockIdx.x * blockDim.x + threadIdx.x;
  if (i >= n8) return;
  const float4* xv = (const float4*)x;
  float4 a = xv[2 * i];
  float4 b = xv[2 * i + 1];
  f16x8 o;
  o[0] = (f16)a.x; o[1] = (f16)a.y; o[2] = (f16)a.z; o[3] = (f16)a.w;
  o[4] = (f16)b.x; o[5] = (f16)b.y; o[6] = (f16)b.z; o[7] = (f16)b.w;
  *(f16x8*)(xo + (size_t)i * 8) = o;
}

__global__ __launch_bounds__(256) void dequant_kernel(const int* __restrict__ q,
                                                      const float* __restrict__ amax,
                                                      f16* __restrict__ wo, int n8) {
  int i = blockIdx.x * blockDim.x + threadIdx.x;
  if (i >= n8) return;
  const int4* qv = (const int4*)q;
  int4 a = qv[2 * i];
  int4 b = qv[2 * i + 1];
  float s = amax[i >> 3] * (1.0f / 7.0f);
  f16x8 o;
  o[0] = (f16)((float)a.x * s); o[1] = (f16)((float)a.y * s);
  o[2] = (f16)((float)a.z * s); o[3] = (f16)((float)a.w * s);
  o[4] = (f16)((float)b.x * s); o[5] = (f16)((float)b.y * s);
  o[6] = (f16)((float)b.z * s); o[7] = (f16)((float)b.w * s);
  *(f16x8*)(wo + (size_t)i * 8) = o;
}

// LDS map (bytes): A slot(parity p, khalf h) @ (p*2+h)*16384 ; B slot @ 65536 + (p*2+h)*16384.
// Each slot: K-half tile 256 rows x 32 f16, stored as [128 LDS rows][128 B] with
// swizzle: linear pos (r,c) holds global (ra = 2r + (c'>>6), kbyte = c'&63), c' = c ^ ((r&7)<<4).
__global__ __launch_bounds__(512, 2) void gemm_f16_bt(const f16* __restrict__ A,
                                                      const f16* __restrict__ B,
                                                      const float* __restrict__ bias,
                                                      float* __restrict__ C) {
  __shared__ __align__(16) char lds[131072];

  const int tid = threadIdx.x;
  const int w = tid >> 6;
  const int l = tid & 63;
  const int wr = w >> 2;  // 0..1 : wave row (128 rows of M each)
  const int wc = w & 3;   // 0..3 : wave col (64 cols of N each)

  // bijective XCD swizzle: nwg = 1376 = 8 * 172
  const int wg = blockIdx.x;
  const int swz = (wg & 7) * 172 + (wg >> 3);
  const int mt = swz / 43;
  const int nt = swz % 43;
  const int m0 = mt * 256;
  const int n0 = nt * 256;

  // per-lane fragment read offset (byte, slot-local); ra = R0 + lr with R0 % 16 == 0:
  // pos = (R0>>1)*128 + (lr>>1)*128 + ((((lr&1)<<6)|(g<<4)) ^ (((lr>>1)&7)<<4))
  const int lr = l & 15;
  const int g = l >> 4;
  const int laneoff = ((lr >> 1) << 7) | (((((lr & 1) << 6) | (g << 4))) ^ (((lr >> 1) & 7) << 4));

  // staging source pointers (pre-swizzled): instr j covers unit chunk (j*8+w)*1024 + l*16
  const char* Asrc[2];
  const char* Bsrc[2];
#pragma unroll
  for (int j = 0; j < 2; ++j) {
    const int u = ((j * 8 + w) << 10) + l * 16;
    const int r = u >> 7;
    const int cp = (u & 127) ^ ((r & 7) << 4);
    const int ra = 2 * r + (cp >> 6);
    const int kb = cp & 63;
    Asrc[j] = (const char*)A + (size_t)(m0 + ra) * (K_DIM * 2) + kb;
    Bsrc[j] = (const char*)B + (size_t)(n0 + ra) * (K_DIM * 2) + kb;
  }

  char* ldsc = (char*)lds;

  f32x4 acc[8][4];
#pragma unroll
  for (int i = 0; i < 8; ++i)
#pragma unroll
    for (int j = 0; j < 4; ++j) acc[i][j] = (f32x4){0.f, 0.f, 0.f, 0.f};

  // prologue: stage tile 0 into parity 0, order A0,B0,A1,B1 (8 loads/wave)
#pragma unroll
  for (int h = 0; h < 2; ++h) {
    const int koff = h * 64;  // bytes along K
    char* dA = ldsc + h * 16384 + w * 1024;
    gload16(Asrc[0] + koff, dA);
    gload16(Asrc[1] + koff, dA + 8192);
    char* dB = ldsc + 65536 + h * 16384 + w * 1024;
    gload16(Bsrc[0] + koff, dB);
    gload16(Bsrc[1] + koff, dB + 8192);
  }
  asm volatile("s_waitcnt vmcnt(4)" ::: "memory");  // A0,B0 of tile 0 landed
  __builtin_amdgcn_s_barrier();

  for (int t = 0; t < NT_K; ++t) {
    const int p = t & 1;
    const int pn = p ^ 1;
    const int tn = (t + 1 < NT_K) ? (t + 1) : (NT_K - 1);  // clamped: last tile restages (harmless)
    const int kA = tn * 128;                                // byte k-offset of staged tile
    const int Ab = p * 32768;
    const int Bb = 65536 + p * 32768;
    const int An = pn * 32768;
    const int Bn = 65536 + pn * 32768;

    f16x8 bf[4];
    f16x8 af[4];
#pragma unroll
    for (int kk = 0; kk < 2; ++kk) {
#pragma unroll
      for (int mh = 0; mh < 2; ++mh) {
        // ds-reads for this quadrant (8 on mh==0, 4 on mh==1)
        if (mh == 0) {
#pragma unroll
          for (int ni = 0; ni < 4; ++ni)
            bf[ni] = *(const f16x8*)(ldsc + Bb + kk * 16384 + ((wc * 64 + ni * 16) << 6) + laneoff);
        }
#pragma unroll
        for (int mi = 0; mi < 4; ++mi)
          af[mi] = *(const f16x8*)(ldsc + Ab + kk * 16384 +
                                   ((wr * 128 + mh * 64 + mi * 16) << 6) + laneoff);

        // stage one half-tile of tile tn into opposite parity
        const int pi = kk * 2 + mh;
        if (pi == 0) {
          char* d = ldsc + An + w * 1024;
          gload16(Asrc[0] + kA, d); gload16(Asrc[1] + kA, d + 8192);
        } else if (pi == 1) {
          char* d = ldsc + Bn + w * 1024;
          gload16(Bsrc[0] + kA, d); gload16(Bsrc[1] + kA, d + 8192);
        } else if (pi == 2) {
          char* d = ldsc + An + 16384 + w * 1024;
          gload16(Asrc[0] + kA + 64, d); gload16(Asrc[1] + kA + 64, d + 8192);
        } else {
          char* d = ldsc + Bn + 16384 + w * 1024;
          gload16(Bsrc[0] + kA + 64, d); gload16(Bsrc[1] + kA + 64, d + 8192);
        }

        __builtin_amdgcn_s_barrier();
        __builtin_amdgcn_s_setprio(1);
#pragma unroll
        for (int mi = 0; mi < 4; ++mi)
#pragma unroll
          for (int ni = 0; ni < 4; ++ni)
            acc[mh * 4 + mi][ni] = __builtin_amdgcn_mfma_f32_16x16x32_f16(
                af[mi], bf[ni], acc[mh * 4 + mi][ni], 0, 0, 0);
        __builtin_amdgcn_s_setprio(0);
        // counted waits: ph1 confirms A1,B1 of current staged set; ph3 confirms A0,B0 of next tile
        if (pi == 1) asm volatile("s_waitcnt vmcnt(4)" ::: "memory");
        if (pi == 3) asm volatile("s_waitcnt vmcnt(4)" ::: "memory");
        __builtin_amdgcn_s_barrier();
      }
    }
  }

  // epilogue: C/D layout col = lane&15, row = (lane>>4)*4 + j
  const int orow = g * 4;
  float bv[4];
#pragma unroll
  for (int ni = 0; ni < 4; ++ni) bv[ni] = bias[n0 + wc * 64 + ni * 16 + lr];
#pragma unroll
  for (int mi = 0; mi < 8; ++mi) {
    const int row = m0 + wr * 128 + mi * 16 + orow;
#pragma unroll
    for (int ni = 0; ni < 4; ++ni) {
      const size_t cb = (size_t)row * N_DIM + (n0 + wc * 64 + ni * 16 + lr);
#pragma unroll
      for (int j = 0; j < 4; ++j) C[cb + (size_t)j * N_DIM] = acc[mi][ni][j] + bv[ni];
    }
  }
}

extern "C" void kernel_launch(void* const* d_in, const int* in_sizes, int n_in,
                              void* d_out, int out_size, void* d_ws, size_t ws_size,
                              hipStream_t stream) {
  const float* x = (const float*)d_in[0];
  const int* wq = (const int*)d_in[1];
  const float* amax = (const float*)d_in[2];
  const float* bias = (const float*)d_in[3];
  float* out = (float*)d_out;

  f16* Xh = (f16*)d_ws;                                       // 64 MB
  f16* Wh = (f16*)((char*)d_ws + (size_t)M_DIM * K_DIM * 2);  // 90 MB

  {
    int n8 = M_DIM * K_DIM / 8;
    cvt_x_kernel<<<n8 / 256, 256, 0, stream>>>(x, Xh, n8);
  }
  {
    int n8 = N_DIM * K_DIM / 8;
    dequant_kernel<<<n8 / 256, 256, 0, stream>>>(wq, amax, Wh, n8);
  }
  {
    dim3 grid((M_DIM / 256) * (N_DIM / 256));  // 32*43 = 1376
    gemm_f16_bt<<<grid, 512, 0, stream>>>(Xh, Wh, bias, out);
  }
}